// Round 3
// baseline (275.547 us; speedup 1.0000x reference)
//
#include <hip/hip_runtime.h>
#include <hip/hip_bf16.h>
#include <stdint.h>

// Problem dims
#define B_  16
#define T_  2048
#define D_  512
#define I_  1024
#define K_  31
#define M_  (B_ * T_)   // 32768

typedef __attribute__((ext_vector_type(8))) __bf16 bf16x8;
typedef __attribute__((ext_vector_type(4))) float  f32x4;

__device__ __forceinline__ unsigned short f2bf(float f) {
    union { float f; uint32_t u; } v; v.f = f;
    uint32_t u = v.u;
    uint32_t r = (u + 0x7FFFu + ((u >> 16) & 1u)) >> 16;
    return (unsigned short)r;
}
__device__ __forceinline__ float bf2f(unsigned short h) {
    union { uint32_t u; float f; } v; v.u = ((uint32_t)h) << 16;
    return v.f;
}

__device__ __forceinline__ void gload_lds16(const void* g, void* l) {
    __builtin_amdgcn_global_load_lds(
        (const __attribute__((address_space(1))) unsigned int*)g,
        (__attribute__((address_space(3))) unsigned int*)l, 16, 0, 0);
}

// ---------------- prep: cast weights to bf16 ----------------
__global__ __launch_bounds__(256) void prep_weights(
    const float* __restrict__ w1, const float* __restrict__ w2,
    unsigned short* __restrict__ w1b, unsigned short* __restrict__ w2b)
{
    int i = blockIdx.x * 256 + threadIdx.x;
    const int n1 = 2 * I_ * D_;   // 1048576
    const int n2 = D_ * I_;       // 524288
    if (i < n1) w1b[i] = f2bf(w1[i]);
    if (i < n2) w2b[i] = f2bf(w2[i]);
}

// ---------------- LayerNorm: fp32 -> bf16 xn ----------------
__global__ __launch_bounds__(256) void ln_kernel(
    const float* __restrict__ x, const float* __restrict__ gam,
    const float* __restrict__ bet, unsigned short* __restrict__ xn)
{
    int row  = blockIdx.x * 4 + (threadIdx.x >> 6);
    int lane = threadIdx.x & 63;
    const float* xr = x + (size_t)row * D_ + lane * 8;
    float4 a0 = *(const float4*)xr;
    float4 a1 = *(const float4*)(xr + 4);
    float xs[8] = {a0.x, a0.y, a0.z, a0.w, a1.x, a1.y, a1.z, a1.w};

    float s = xs[0]+xs[1]+xs[2]+xs[3]+xs[4]+xs[5]+xs[6]+xs[7];
    #pragma unroll
    for (int off = 32; off; off >>= 1) s += __shfl_xor(s, off);
    float mu = s * (1.0f / D_);

    float q = 0.f;
    #pragma unroll
    for (int j = 0; j < 8; ++j) { float d = xs[j] - mu; q += d * d; }
    #pragma unroll
    for (int off = 32; off; off >>= 1) q += __shfl_xor(q, off);
    float rstd = rsqrtf(q * (1.0f / D_) + 1e-5f);

    float4 g0 = *(const float4*)(gam + lane * 8);
    float4 g1 = *(const float4*)(gam + lane * 8 + 4);
    float4 e0 = *(const float4*)(bet + lane * 8);
    float4 e1 = *(const float4*)(bet + lane * 8 + 4);
    float gs[8] = {g0.x, g0.y, g0.z, g0.w, g1.x, g1.y, g1.z, g1.w};
    float bs[8] = {e0.x, e0.y, e0.z, e0.w, e1.x, e1.y, e1.z, e1.w};

    unsigned short o[8];
    #pragma unroll
    for (int j = 0; j < 8; ++j) o[j] = f2bf((xs[j] - mu) * rstd * gs[j] + bs[j]);
    uint4 pk;
    pk.x = (uint32_t)o[0] | ((uint32_t)o[1] << 16);
    pk.y = (uint32_t)o[2] | ((uint32_t)o[3] << 16);
    pk.z = (uint32_t)o[4] | ((uint32_t)o[5] << 16);
    pk.w = (uint32_t)o[6] | ((uint32_t)o[7] << 16);
    *(uint4*)(xn + (size_t)row * D_ + lane * 8) = pk;
}

// ======================================================================
// 8-phase 256x256 GEMM core (T2 swizzle + T3/T4 counted vmcnt + T5 setprio)
// LDS layout per buffer: A [256][64] bf16 (32KB) then B [256][64] (32KB).
// Swizzle: within a 128B row, col_byte ^= (row&7)<<4; applied inversely on
// the GLOBAL source of global_load_lds (dest stays linear), and on ds_read.
// Prefetch schedule (per-thread slots, 4 A + 4 B per K-tile):
//   tile t+1: B2,B3 @ t.ph1 ; A0,A1 @ t.ph2 ; A2,A3 @ t.ph3 ; B0,B1 @ t-1.ph4
//   -> at t.ph4 wait vmcnt(2) (only t+2's B0,B1 in flight).
// ph4's issues write buf[cur].B, whose reads completed in ph3 (regs) — safe.
// ======================================================================

#define PHASE_SYNC_PRE()  do { \
    __builtin_amdgcn_s_barrier(); \
    asm volatile("s_waitcnt lgkmcnt(0)" ::: "memory"); \
    __builtin_amdgcn_sched_barrier(0); \
    __builtin_amdgcn_s_setprio(1); } while (0)

#define PHASE_SYNC_POST() do { \
    __builtin_amdgcn_s_setprio(0); \
    __builtin_amdgcn_sched_barrier(0); \
    __builtin_amdgcn_s_barrier(); } while (0)

// ---------------- GEMM1: xn[32768,512] x w1b^T -> SwiGLU -> u bf16 [32768,1024]
// B tile rows interleaved: lds row 2c = a-channel, 2c+1 = g-channel.
__global__ __launch_bounds__(512, 2) void gemm1_kernel(
    const unsigned short* __restrict__ xn,   // [32768][512]
    const unsigned short* __restrict__ w1b,  // [2048][512]
    const float* __restrict__ b1,            // [2048]
    unsigned short* __restrict__ u)          // [32768][1024]
{
    __shared__ __align__(16) unsigned char lds[131072];
    const int tid  = threadIdx.x;
    const int lane = tid & 63;
    const int wv   = tid >> 6;
    const int wm   = wv >> 2;   // 0..1
    const int wn   = wv & 3;    // 0..3

    // bijective XCD swizzle: nwg=1024, 8 n-blocks fastest within chunk
    const int bid = blockIdx.x;
    const int sw  = (bid & 7) * 128 + (bid >> 3);
    const int jb  = sw & 7;     // channel block (128 out ch each)
    const int m0  = (sw >> 3) * 256;

    // staging source addresses (pre-swizzled global)
    const unsigned short* aga[4];
    const unsigned short* agb[4];
    #pragma unroll
    for (int j = 0; j < 4; ++j) {
        int s = tid + j * 512;
        int row = s >> 3, cb = s & 7;
        int kk = (cb ^ (row & 7)) * 8;
        aga[j] = xn + (size_t)(m0 + row) * D_ + kk;
        int ch = jb * 128 + (row >> 1);
        int wrow = (row & 1) ? (1024 + ch) : ch;
        agb[j] = w1b + (size_t)wrow * D_ + kk;
    }
    const int ldsA = tid * 16;
    const int ldsB = 32768 + tid * 16;

#define G1_ISSUE_A(j, c) do { \
    gload_lds16(aga[j], lds + (c) * 65536 + ldsA + (j) * 8192); \
    aga[j] += 64; } while (0)
#define G1_ISSUE_B(j, c) do { \
    gload_lds16(agb[j], lds + (c) * 65536 + ldsB + (j) * 8192); \
    agb[j] += 64; } while (0)

    const int l15 = lane & 15;
    const int kq  = (lane >> 4) << 4;   // 0,16,32,48 byte col within k-half

#define G1_READ_A(fm, kh, c) \
    (*(const bf16x8*)(lds + (c) * 65536 + (wm * 128 + (fm) * 16 + l15) * 128 + \
        (((kh) * 64 + kq) ^ (((wm * 128 + (fm) * 16 + l15) & 7) << 4))))
#define G1_READ_B(fn, kh, c) \
    (*(const bf16x8*)(lds + (c) * 65536 + 32768 + (wn * 64 + (fn) * 16 + l15) * 128 + \
        (((kh) * 64 + kq) ^ (((wn * 64 + (fn) * 16 + l15) & 7) << 4))))

    f32x4 acc[8][4];
    #pragma unroll
    for (int i = 0; i < 8; ++i)
        #pragma unroll
        for (int n = 0; n < 4; ++n) acc[i][n] = (f32x4){0.f, 0.f, 0.f, 0.f};

    const int NT = D_ / 64;   // 8
    // prologue: tile0 all 8 slots, tile1 B0,B1
    G1_ISSUE_B(0, 0); G1_ISSUE_B(1, 0); G1_ISSUE_B(2, 0); G1_ISSUE_B(3, 0);
    G1_ISSUE_A(0, 0); G1_ISSUE_A(1, 0); G1_ISSUE_A(2, 0); G1_ISSUE_A(3, 0);
    G1_ISSUE_B(0, 1); G1_ISSUE_B(1, 1);
    asm volatile("s_waitcnt vmcnt(2)" ::: "memory");
    __builtin_amdgcn_s_barrier();

    for (int t = 0; t < NT; ++t) {
        const int cur = t & 1, nxt = cur ^ 1;
        bf16x8 bf0[4], af[4];
        // ---- phase 1: kh=0, m-half 0
        #pragma unroll
        for (int n = 0; n < 4; ++n) bf0[n] = G1_READ_B(n, 0, cur);
        #pragma unroll
        for (int i = 0; i < 4; ++i) af[i] = G1_READ_A(i, 0, cur);
        if (t + 1 < NT) { G1_ISSUE_B(2, nxt); G1_ISSUE_B(3, nxt); }
        PHASE_SYNC_PRE();
        #pragma unroll
        for (int i = 0; i < 4; ++i)
            #pragma unroll
            for (int n = 0; n < 4; ++n)
                acc[i][n] = __builtin_amdgcn_mfma_f32_16x16x32_bf16(af[i], bf0[n], acc[i][n], 0, 0, 0);
        PHASE_SYNC_POST();
        // ---- phase 2: kh=0, m-half 1
        #pragma unroll
        for (int i = 0; i < 4; ++i) af[i] = G1_READ_A(4 + i, 0, cur);
        if (t + 1 < NT) { G1_ISSUE_A(0, nxt); G1_ISSUE_A(1, nxt); }
        PHASE_SYNC_PRE();
        #pragma unroll
        for (int i = 0; i < 4; ++i)
            #pragma unroll
            for (int n = 0; n < 4; ++n)
                acc[4 + i][n] = __builtin_amdgcn_mfma_f32_16x16x32_bf16(af[i], bf0[n], acc[4 + i][n], 0, 0, 0);
        PHASE_SYNC_POST();
        // ---- phase 3: kh=1, m-half 0
        #pragma unroll
        for (int n = 0; n < 4; ++n) bf0[n] = G1_READ_B(n, 1, cur);
        #pragma unroll
        for (int i = 0; i < 4; ++i) af[i] = G1_READ_A(i, 1, cur);
        if (t + 1 < NT) { G1_ISSUE_A(2, nxt); G1_ISSUE_A(3, nxt); }
        PHASE_SYNC_PRE();
        #pragma unroll
        for (int i = 0; i < 4; ++i)
            #pragma unroll
            for (int n = 0; n < 4; ++n)
                acc[i][n] = __builtin_amdgcn_mfma_f32_16x16x32_bf16(af[i], bf0[n], acc[i][n], 0, 0, 0);
        PHASE_SYNC_POST();
        // ---- phase 4: kh=1, m-half 1  (issues tile t+2's B0,B1 into buf[cur].B)
        #pragma unroll
        for (int i = 0; i < 4; ++i) af[i] = G1_READ_A(4 + i, 1, cur);
        if (t + 2 < NT) { G1_ISSUE_B(0, cur); G1_ISSUE_B(1, cur); }
        PHASE_SYNC_PRE();
        #pragma unroll
        for (int i = 0; i < 4; ++i)
            #pragma unroll
            for (int n = 0; n < 4; ++n)
                acc[4 + i][n] = __builtin_amdgcn_mfma_f32_16x16x32_bf16(af[i], bf0[n], acc[4 + i][n], 0, 0, 0);
        __builtin_amdgcn_s_setprio(0);
        __builtin_amdgcn_sched_barrier(0);
        if (t + 2 < NT)      asm volatile("s_waitcnt vmcnt(2)" ::: "memory");
        else if (t + 1 < NT) asm volatile("s_waitcnt vmcnt(0)" ::: "memory");
        __builtin_amdgcn_s_barrier();
    }

    // epilogue: a/g interleaved on adjacent lanes -> shfl_xor(1) pairing
    const int rQ = (lane >> 4) * 4;
    #pragma unroll
    for (int nf = 0; nf < 4; ++nf) {
        int n  = wn * 64 + nf * 16 + l15;
        int ch = jb * 128 + (n >> 1);
        float ba = b1[ch];
        float bg = b1[1024 + ch];
        #pragma unroll
        for (int mf = 0; mf < 8; ++mf) {
            #pragma unroll
            for (int r = 0; r < 4; ++r) {
                float vv = acc[mf][nf][r];
                float ov = __shfl_xor(vv, 1);
                if (!(lane & 1)) {
                    float a = vv + ba, g = ov + bg;
                    float sg = g / (1.0f + __expf(-g));
                    int row = m0 + wm * 128 + mf * 16 + rQ + r;
                    u[(size_t)row * I_ + ch] = f2bf(a * sg);
                }
            }
        }
    }
#undef G1_ISSUE_A
#undef G1_ISSUE_B
#undef G1_READ_A
#undef G1_READ_B
}

// ---------------- depthwise conv K=31 + bias + PReLU: u bf16 -> v bf16 ----------------
__global__ __launch_bounds__(256) void dwconv_kernel(
    const unsigned short* __restrict__ u, const float* __restrict__ dw,
    const float* __restrict__ dwb, const float* __restrict__ alpha,
    unsigned short* __restrict__ v)
{
    // grid: x = T/256 = 8, y = I/64 = 16, z = B = 16
    __shared__ __align__(16) unsigned short su[286][64];
    const int tid     = threadIdx.x;
    const int c0      = blockIdx.y * 64;
    const int b       = blockIdx.z;
    const int tile_t0 = blockIdx.x * 256;

    #pragma unroll
    for (int it = 0; it < 9; ++it) {
        int r = it * 32 + (tid >> 3);
        if (r < 286) {
            int tt = tile_t0 - 15 + r;
            int cc = (tid & 7) * 8;
            uint4 val = {0u, 0u, 0u, 0u};
            if (tt >= 0 && tt < T_)
                val = *(const uint4*)(u + ((size_t)b * T_ + tt) * I_ + c0 + cc);
            *(uint4*)(&su[r][cc]) = val;
        }
    }
    __syncthreads();

    const int c  = tid & 63;
    const int tb = (tid >> 6) * 64;

    float dwk[K_];
    #pragma unroll
    for (int k = 0; k < K_; ++k) dwk[k] = dw[(c0 + c) * K_ + k];
    const float bia = dwb[c0 + c], al = alpha[c0 + c];

    unsigned short* vb = v + ((size_t)b * T_ + tile_t0 + tb) * I_ + c0 + c;

    #pragma unroll
    for (int chk = 0; chk < 4; ++chk) {
        float w[46];
        #pragma unroll
        for (int j = 0; j < 46; ++j)
            w[j] = bf2f(su[tb + chk * 16 + j][c]);
        #pragma unroll
        for (int i = 0; i < 16; ++i) {
            float acc = bia;
            #pragma unroll
            for (int k = 0; k < K_; ++k) acc += w[i + k] * dwk[k];
            float o = acc > 0.f ? acc : al * acc;
            vb[(size_t)(chk * 16 + i) * I_] = f2bf(o);
        }
    }
}

// ---------------- GEMM2: v[32768,1024] x w2b^T + b2 -> out fp32 [32768,512] ----------------
__global__ __launch_bounds__(512, 2) void gemm2_kernel(
    const unsigned short* __restrict__ v,    // [32768][1024]
    const unsigned short* __restrict__ w2b,  // [512][1024]
    const float* __restrict__ b2,            // [512]
    float* __restrict__ out)                 // [32768][512]
{
    __shared__ __align__(16) unsigned char lds[131072];
    const int tid  = threadIdx.x;
    const int lane = tid & 63;
    const int wv   = tid >> 6;
    const int wm   = wv >> 2;
    const int wn   = wv & 3;

    // nwg=256; n fastest so (m, n0/n1) pairs share an XCD chunk
    const int bid = blockIdx.x;
    const int sw  = (bid & 7) * 32 + (bid >> 3);
    const int n0  = (sw & 1) * 256;
    const int m0  = (sw >> 1) * 256;

    const unsigned short* aga[4];
    const unsigned short* agb[4];
    #pragma unroll
    for (int j = 0; j < 4; ++j) {
        int s = tid + j * 512;
        int row = s >> 3, cb = s & 7;
        int kk = (cb ^ (row & 7)) * 8;
        aga[j] = v   + (size_t)(m0 + row) * I_ + kk;
        agb[j] = w2b + (size_t)(n0 + row) * I_ + kk;
    }
    const int ldsA = tid * 16;
    const int ldsB = 32768 + tid * 16;

#define G2_ISSUE_A(j, c) do { \
    gload_lds16(aga[j], lds + (c) * 65536 + ldsA + (j) * 8192); \
    aga[j] += 64; } while (0)
#define G2_ISSUE_B(j, c) do { \
    gload_lds16(agb[j], lds + (c) * 65536 + ldsB + (j) * 8192); \
    agb[j] += 64; } while (0)

    const int l15 = lane & 15;
    const int kq  = (lane >> 4) << 4;

#define G2_READ_A(fm, kh, c) \
    (*(const bf16x8*)(lds + (c) * 65536 + (wm * 128 + (fm) * 16 + l15) * 128 + \
        (((kh) * 64 + kq) ^ (((wm * 128 + (fm) * 16 + l15) & 7) << 4))))
#define G2_READ_B(fn, kh, c) \
    (*(const bf16x8*)(lds + (c) * 65536 + 32768 + (wn * 64 + (fn) * 16 + l15) * 128 + \
        (((kh) * 64 + kq) ^ (((wn * 64 + (fn) * 16 + l15) & 7) << 4))))

    f32x4 acc[8][4];
    #pragma unroll
    for (int i = 0; i < 8; ++i)
        #pragma unroll
        for (int n = 0; n < 4; ++n) acc[i][n] = (f32x4){0.f, 0.f, 0.f, 0.f};

    const int NT = I_ / 64;   // 16
    G2_ISSUE_B(0, 0); G2_ISSUE_B(1, 0); G2_ISSUE_B(2, 0); G2_ISSUE_B(3, 0);
    G2_ISSUE_A(0, 0); G2_ISSUE_A(1, 0); G2_ISSUE_A(2, 0); G2_ISSUE_A(3, 0);
    G2_ISSUE_B(0, 1); G2_ISSUE_B(1, 1);
    asm volatile("s_waitcnt vmcnt(2)" ::: "memory");
    __builtin_amdgcn_s_barrier();

    for (int t = 0; t < NT; ++t) {
        const int cur = t & 1, nxt = cur ^ 1;
        bf16x8 bf0[4], af[4];
        // ---- phase 1
        #pragma unroll
        for (int n = 0; n < 4; ++n) bf0[n] = G2_READ_B(n, 0, cur);
        #pragma unroll
        for (int i = 0; i < 4; ++i) af[i] = G2_READ_A(i, 0, cur);
        if (t + 1 < NT) { G2_ISSUE_B(2, nxt); G2_ISSUE_B(3, nxt); }
        PHASE_SYNC_PRE();
        #pragma unroll
        for (int i = 0; i < 4; ++i)
            #pragma unroll
            for (int n = 0; n < 4; ++n)
                acc[i][n] = __builtin_amdgcn_mfma_f32_16x16x32_bf16(af[i], bf0[n], acc[i][n], 0, 0, 0);
        PHASE_SYNC_POST();
        // ---- phase 2
        #pragma unroll
        for (int i = 0; i < 4; ++i) af[i] = G2_READ_A(4 + i, 0, cur);
        if (t + 1 < NT) { G2_ISSUE_A(0, nxt); G2_ISSUE_A(1, nxt); }
        PHASE_SYNC_PRE();
        #pragma unroll
        for (int i = 0; i < 4; ++i)
            #pragma unroll
            for (int n = 0; n < 4; ++n)
                acc[4 + i][n] = __builtin_amdgcn_mfma_f32_16x16x32_bf16(af[i], bf0[n], acc[4 + i][n], 0, 0, 0);
        PHASE_SYNC_POST();
        // ---- phase 3
        #pragma unroll
        for (int n = 0; n < 4; ++n) bf0[n] = G2_READ_B(n, 1, cur);
        #pragma unroll
        for (int i = 0; i < 4; ++i) af[i] = G2_READ_A(i, 1, cur);
        if (t + 1 < NT) { G2_ISSUE_A(2, nxt); G2_ISSUE_A(3, nxt); }
        PHASE_SYNC_PRE();
        #pragma unroll
        for (int i = 0; i < 4; ++i)
            #pragma unroll
            for (int n = 0; n < 4; ++n)
                acc[i][n] = __builtin_amdgcn_mfma_f32_16x16x32_bf16(af[i], bf0[n], acc[i][n], 0, 0, 0);
        PHASE_SYNC_POST();
        // ---- phase 4
        #pragma unroll
        for (int i = 0; i < 4; ++i) af[i] = G2_READ_A(4 + i, 1, cur);
        if (t + 2 < NT) { G2_ISSUE_B(0, cur); G2_ISSUE_B(1, cur); }
        PHASE_SYNC_PRE();
        #pragma unroll
        for (int i = 0; i < 4; ++i)
            #pragma unroll
            for (int n = 0; n < 4; ++n)
                acc[4 + i][n] = __builtin_amdgcn_mfma_f32_16x16x32_bf16(af[i], bf0[n], acc[4 + i][n], 0, 0, 0);
        __builtin_amdgcn_s_setprio(0);
        __builtin_amdgcn_sched_barrier(0);
        if (t + 2 < NT)      asm volatile("s_waitcnt vmcnt(2)" ::: "memory");
        else if (t + 1 < NT) asm volatile("s_waitcnt vmcnt(0)" ::: "memory");
        __builtin_amdgcn_s_barrier();
    }

    const int rQ = (lane >> 4) * 4;
    #pragma unroll
    for (int nf = 0; nf < 4; ++nf) {
        int col = n0 + wn * 64 + nf * 16 + l15;
        float bb = b2[col];
        #pragma unroll
        for (int mf = 0; mf < 8; ++mf) {
            #pragma unroll
            for (int r = 0; r < 4; ++r) {
                int row = m0 + wm * 128 + mf * 16 + rQ + r;
                out[(size_t)row * D_ + col] = acc[mf][nf][r] + bb;
            }
        }
    }
#undef G2_ISSUE_A
#undef G2_ISSUE_B
#undef G2_READ_A
#undef G2_READ_B
}

extern "C" void kernel_launch(void* const* d_in, const int* in_sizes, int n_in,
                              void* d_out, int out_size, void* d_ws, size_t ws_size,
                              hipStream_t stream) {
    const float* x     = (const float*)d_in[0];
    const float* ln_g  = (const float*)d_in[1];
    const float* ln_b  = (const float*)d_in[2];
    const float* w1    = (const float*)d_in[3];
    const float* b1    = (const float*)d_in[4];
    const float* dw    = (const float*)d_in[5];
    const float* dwb   = (const float*)d_in[6];
    const float* alpha = (const float*)d_in[7];
    const float* w2    = (const float*)d_in[8];
    const float* b2    = (const float*)d_in[9];
    float* out = (float*)d_out;

    char* ws = (char*)d_ws;
    unsigned short* xn  = (unsigned short*)(ws);                 // 32 MB
    unsigned short* u   = (unsigned short*)(ws + 33554432);      // 64 MB
    unsigned short* v   = (unsigned short*)(ws + 100663296);     // 64 MB
    unsigned short* w1b = (unsigned short*)(ws + 167772160);     // 2 MB
    unsigned short* w2b = (unsigned short*)(ws + 169869312);     // 1 MB

    prep_weights<<<4096, 256, 0, stream>>>(w1, w2, w1b, w2b);
    ln_kernel<<<M_ / 4, 256, 0, stream>>>(x, ln_g, ln_b, xn);
    gemm1_kernel<<<(M_ / 256) * (I_ / 128), 512, 0, stream>>>(xn, w1b, b1, u);  // 1024 blocks
    dim3 gc(T_ / 256, I_ / 64, B_);           // (8, 16, 16)
    dwconv_kernel<<<gc, 256, 0, stream>>>(u, dw, dwb, alpha, v);
    gemm2_kernel<<<(M_ / 256) * (D_ / 256), 512, 0, stream>>>(v, w2b, b2, out); // 256 blocks
}

// Round 4
// 214.559 us; speedup vs baseline: 1.2842x; 1.2842x over previous
//
#include <hip/hip_runtime.h>
#include <hip/hip_bf16.h>
#include <stdint.h>

// Problem dims
#define B_  16
#define T_  2048
#define D_  512
#define I_  1024
#define K_  31
#define M_  (B_ * T_)   // 32768

typedef __attribute__((ext_vector_type(8))) __bf16 bf16x8;
typedef __attribute__((ext_vector_type(4))) float  f32x4;

__device__ __forceinline__ unsigned short f2bf(float f) {
    union { float f; uint32_t u; } v; v.f = f;
    uint32_t u = v.u;
    uint32_t r = (u + 0x7FFFu + ((u >> 16) & 1u)) >> 16;
    return (unsigned short)r;
}
__device__ __forceinline__ float bf2f(unsigned short h) {
    union { uint32_t u; float f; } v; v.u = ((uint32_t)h) << 16;
    return v.f;
}

__device__ __forceinline__ void gload_lds16(const void* g, void* l) {
    __builtin_amdgcn_global_load_lds(
        (const __attribute__((address_space(1))) unsigned int*)g,
        (__attribute__((address_space(3))) unsigned int*)l, 16, 0, 0);
}

// ---------------- prep: cast weights to bf16 ----------------
__global__ __launch_bounds__(256) void prep_weights(
    const float* __restrict__ w1, const float* __restrict__ w2,
    unsigned short* __restrict__ w1b, unsigned short* __restrict__ w2b)
{
    int i = blockIdx.x * 256 + threadIdx.x;
    const int n1 = 2 * I_ * D_;
    const int n2 = D_ * I_;
    if (i < n1) w1b[i] = f2bf(w1[i]);
    if (i < n2) w2b[i] = f2bf(w2[i]);
}

// ---------------- LayerNorm: fp32 -> bf16 xn ----------------
__global__ __launch_bounds__(256) void ln_kernel(
    const float* __restrict__ x, const float* __restrict__ gam,
    const float* __restrict__ bet, unsigned short* __restrict__ xn)
{
    int row  = blockIdx.x * 4 + (threadIdx.x >> 6);
    int lane = threadIdx.x & 63;
    const float* xr = x + (size_t)row * D_ + lane * 8;
    float4 a0 = *(const float4*)xr;
    float4 a1 = *(const float4*)(xr + 4);
    float xs[8] = {a0.x, a0.y, a0.z, a0.w, a1.x, a1.y, a1.z, a1.w};

    float s = xs[0]+xs[1]+xs[2]+xs[3]+xs[4]+xs[5]+xs[6]+xs[7];
    #pragma unroll
    for (int off = 32; off; off >>= 1) s += __shfl_xor(s, off);
    float mu = s * (1.0f / D_);

    float q = 0.f;
    #pragma unroll
    for (int j = 0; j < 8; ++j) { float d = xs[j] - mu; q += d * d; }
    #pragma unroll
    for (int off = 32; off; off >>= 1) q += __shfl_xor(q, off);
    float rstd = rsqrtf(q * (1.0f / D_) + 1e-5f);

    float4 g0 = *(const float4*)(gam + lane * 8);
    float4 g1 = *(const float4*)(gam + lane * 8 + 4);
    float4 e0 = *(const float4*)(bet + lane * 8);
    float4 e1 = *(const float4*)(bet + lane * 8 + 4);
    float gs[8] = {g0.x, g0.y, g0.z, g0.w, g1.x, g1.y, g1.z, g1.w};
    float bs[8] = {e0.x, e0.y, e0.z, e0.w, e1.x, e1.y, e1.z, e1.w};

    unsigned short o[8];
    #pragma unroll
    for (int j = 0; j < 8; ++j) o[j] = f2bf((xs[j] - mu) * rstd * gs[j] + bs[j]);
    uint4 pk;
    pk.x = (uint32_t)o[0] | ((uint32_t)o[1] << 16);
    pk.y = (uint32_t)o[2] | ((uint32_t)o[3] << 16);
    pk.z = (uint32_t)o[4] | ((uint32_t)o[5] << 16);
    pk.w = (uint32_t)o[6] | ((uint32_t)o[7] << 16);
    *(uint4*)(xn + (size_t)row * D_ + lane * 8) = pk;
}

// ======================================================================
// Shared 8-phase 256x256 GEMM machinery (K-loop unrolled x2, compile-time
// buffer index, precomputed swizzled LDS bases, clean dbuf schedule).
// LDS: buf c at c*65536: A [256][64]bf16 @0, B [256][64]bf16 @32768.
// Swizzle: LDS[row][colbyte] holds global[row][colbyte ^ ((row&7)<<4)];
// gload dest linear, source pre-swizzled, reads apply same XOR.
// Schedule per K-tile t (4 phases, 16 MFMA each):
//  P1: read B0-3,A0-3(kh0)[cur]; issue t+1: B*4,A0,A2 -> nxt; MFMA m0-3;
//      vmcnt(6|0) + barrier   (waits t's A1,A3, issued 3 phases ago)
//  P2: read A4-7(kh0); issue t+1: A1,A3; MFMA m4-7
//  P3: read B0-3,A0-3(kh1); MFMA m0-3
//  P4: read A4-7(kh1); MFMA m4-7; vmcnt(2) + barrier (6-group of t+1 done)
// ======================================================================

#define PRE_() do { \
    __builtin_amdgcn_s_barrier(); \
    asm volatile("s_waitcnt lgkmcnt(0)" ::: "memory"); \
    __builtin_amdgcn_sched_barrier(0); \
    __builtin_amdgcn_s_setprio(1); } while (0)

#define POST0_() do { \
    __builtin_amdgcn_s_setprio(0); \
    __builtin_amdgcn_sched_barrier(0); \
    __builtin_amdgcn_s_barrier(); } while (0)

#define POSTV_(six) do { \
    __builtin_amdgcn_s_setprio(0); \
    __builtin_amdgcn_sched_barrier(0); \
    if (six) asm volatile("s_waitcnt vmcnt(6)" ::: "memory"); \
    else     asm volatile("s_waitcnt vmcnt(0)" ::: "memory"); \
    __builtin_amdgcn_s_barrier(); } while (0)

#define POSTW_(two) do { \
    __builtin_amdgcn_s_setprio(0); \
    __builtin_amdgcn_sched_barrier(0); \
    if (two) asm volatile("s_waitcnt vmcnt(2)" ::: "memory"); \
    __builtin_amdgcn_s_barrier(); } while (0)

#define RD(base, idx) (*(const bf16x8*)(lds + (base) + (idx) * 2048))
#define MF(m, n, a, b) \
    acc[m][n] = __builtin_amdgcn_mfma_f32_16x16x32_bf16(a, b, acc[m][n], 0, 0, 0)

#define ISSUE_A(j, c) do { \
    gload_lds16(agA[j], lds + (c) * 65536 + tid * 16 + (j) * 8192); \
    agA[j] += 64; } while (0)
#define ISSUE_B(j, c) do { \
    gload_lds16(agB[j], lds + (c) * 65536 + 32768 + tid * 16 + (j) * 8192); \
    agB[j] += 64; } while (0)
#define ISSUE6(c) do { ISSUE_B(0,c); ISSUE_B(1,c); ISSUE_B(2,c); ISSUE_B(3,c); \
                       ISSUE_A(0,c); ISSUE_A(2,c); } while (0)
#define ISSUE2(c) do { ISSUE_A(1,c); ISSUE_A(3,c); } while (0)

#define KTILE(CUR, NXT, DOISS, VM6) do { \
    bf16x8 af0, af1, af2, af3, bb0, bb1, bb2, bb3; \
    bb0 = RD(bB0[CUR],0); bb1 = RD(bB0[CUR],1); bb2 = RD(bB0[CUR],2); bb3 = RD(bB0[CUR],3); \
    af0 = RD(bA0[CUR],0); af1 = RD(bA0[CUR],1); af2 = RD(bA0[CUR],2); af3 = RD(bA0[CUR],3); \
    if (DOISS) { ISSUE6(NXT); } \
    PRE_(); \
    MF(0,0,af0,bb0); MF(0,1,af0,bb1); MF(0,2,af0,bb2); MF(0,3,af0,bb3); \
    MF(1,0,af1,bb0); MF(1,1,af1,bb1); MF(1,2,af1,bb2); MF(1,3,af1,bb3); \
    MF(2,0,af2,bb0); MF(2,1,af2,bb1); MF(2,2,af2,bb2); MF(2,3,af2,bb3); \
    MF(3,0,af3,bb0); MF(3,1,af3,bb1); MF(3,2,af3,bb2); MF(3,3,af3,bb3); \
    POSTV_(VM6); \
    af0 = RD(bA0[CUR],4); af1 = RD(bA0[CUR],5); af2 = RD(bA0[CUR],6); af3 = RD(bA0[CUR],7); \
    if (DOISS) { ISSUE2(NXT); } \
    PRE_(); \
    MF(4,0,af0,bb0); MF(4,1,af0,bb1); MF(4,2,af0,bb2); MF(4,3,af0,bb3); \
    MF(5,0,af1,bb0); MF(5,1,af1,bb1); MF(5,2,af1,bb2); MF(5,3,af1,bb3); \
    MF(6,0,af2,bb0); MF(6,1,af2,bb1); MF(6,2,af2,bb2); MF(6,3,af2,bb3); \
    MF(7,0,af3,bb0); MF(7,1,af3,bb1); MF(7,2,af3,bb2); MF(7,3,af3,bb3); \
    POST0_(); \
    bb0 = RD(bB1[CUR],0); bb1 = RD(bB1[CUR],1); bb2 = RD(bB1[CUR],2); bb3 = RD(bB1[CUR],3); \
    af0 = RD(bA1[CUR],0); af1 = RD(bA1[CUR],1); af2 = RD(bA1[CUR],2); af3 = RD(bA1[CUR],3); \
    PRE_(); \
    MF(0,0,af0,bb0); MF(0,1,af0,bb1); MF(0,2,af0,bb2); MF(0,3,af0,bb3); \
    MF(1,0,af1,bb0); MF(1,1,af1,bb1); MF(1,2,af1,bb2); MF(1,3,af1,bb3); \
    MF(2,0,af2,bb0); MF(2,1,af2,bb1); MF(2,2,af2,bb2); MF(2,3,af2,bb3); \
    MF(3,0,af3,bb0); MF(3,1,af3,bb1); MF(3,2,af3,bb2); MF(3,3,af3,bb3); \
    POST0_(); \
    af0 = RD(bA1[CUR],4); af1 = RD(bA1[CUR],5); af2 = RD(bA1[CUR],6); af3 = RD(bA1[CUR],7); \
    PRE_(); \
    MF(4,0,af0,bb0); MF(4,1,af0,bb1); MF(4,2,af0,bb2); MF(4,3,af0,bb3); \
    MF(5,0,af1,bb0); MF(5,1,af1,bb1); MF(5,2,af1,bb2); MF(5,3,af1,bb3); \
    MF(6,0,af2,bb0); MF(6,1,af2,bb1); MF(6,2,af2,bb2); MF(6,3,af2,bb3); \
    MF(7,0,af3,bb0); MF(7,1,af3,bb1); MF(7,2,af3,bb2); MF(7,3,af3,bb3); \
    POSTW_(DOISS); \
} while (0)

// ---------------- GEMM1: xn[32768,512] x w1b^T -> SwiGLU -> u bf16 [32768,1024]
// B-tile row n: channel chl = (n>>5)*16 + (n&15) of this jb block (128 ch),
// gate = n&16 (0 = a-row, 16 = g-row)  -> SwiGLU pairs are frag-local.
__global__ __launch_bounds__(512, 2) void gemm1_kernel(
    const unsigned short* __restrict__ xn,
    const unsigned short* __restrict__ w1b,
    const float* __restrict__ b1,
    unsigned short* __restrict__ u)
{
    __shared__ __align__(16) unsigned char lds[131072];
    const int tid  = threadIdx.x;
    const int lane = tid & 63;
    const int wv   = tid >> 6;
    const int wm   = wv >> 2;   // 0..1
    const int wn   = wv & 3;    // 0..3

    const int bid = blockIdx.x;                 // nwg = 1024
    const int sw  = (bid & 7) * 128 + (bid >> 3);
    const int jb  = sw & 7;
    const int m0  = (sw >> 3) * 256;

    // staging source pointers (pre-swizzled column)
    const unsigned short* agA[4];
    const unsigned short* agB[4];
    {
        const int srow = tid >> 3;
        const int scb  = tid & 7;
        #pragma unroll
        for (int j = 0; j < 4; ++j) {
            int row = j * 64 + srow;
            int kk  = (scb ^ (row & 7)) * 8;
            agA[j] = xn + (size_t)(m0 + row) * D_ + kk;
            int chl  = ((row >> 5) << 4) + (row & 15);
            int wrow = ((row & 16) ? 1024 : 0) + jb * 128 + chl;
            agB[j] = w1b + (size_t)wrow * D_ + kk;
        }
    }

    // swizzled LDS read bases
    const int l15 = lane & 15;
    const unsigned kq  = (unsigned)((lane >> 4) << 4);
    const unsigned swx = (unsigned)((l15 & 7) << 4);
    const unsigned rA  = (unsigned)(wm * 128 + l15) * 128;
    const unsigned rB  = 32768u + (unsigned)(wn * 64 + l15) * 128;
    const unsigned bA0[2] = {rA + (kq ^ swx),          rA + (kq ^ swx) + 65536u};
    const unsigned bA1[2] = {rA + ((64u + kq) ^ swx),  rA + ((64u + kq) ^ swx) + 65536u};
    const unsigned bB0[2] = {rB + (kq ^ swx),          rB + (kq ^ swx) + 65536u};
    const unsigned bB1[2] = {rB + ((64u + kq) ^ swx),  rB + ((64u + kq) ^ swx) + 65536u};

    f32x4 acc[8][4];
    #pragma unroll
    for (int i = 0; i < 8; ++i)
        #pragma unroll
        for (int n = 0; n < 4; ++n) acc[i][n] = (f32x4){0.f, 0.f, 0.f, 0.f};

    // prologue: tile0 fully staged (6-group then 2-group)
    ISSUE6(0); ISSUE2(0);
    asm volatile("s_waitcnt vmcnt(2)" ::: "memory");
    __builtin_amdgcn_s_barrier();

    const int NT = D_ / 64;   // 8
    for (int tt = 0; tt < NT; tt += 2) {
        KTILE(0, 1, true, true);
        const bool more = (tt + 2 < NT);
        KTILE(1, 0, more, more);
    }

    // epilogue: SwiGLU, frag-local a/g pairing, all lanes store
    const int rQ = (lane >> 4) * 4;
    #pragma unroll
    for (int p = 0; p < 2; ++p) {
        int ch = jb * 128 + wn * 32 + p * 16 + l15;
        float ba = b1[ch];
        float bg = b1[1024 + ch];
        #pragma unroll
        for (int mf = 0; mf < 8; ++mf) {
            #pragma unroll
            for (int r = 0; r < 4; ++r) {
                float a = acc[mf][2 * p][r] + ba;
                float g = acc[mf][2 * p + 1][r] + bg;
                float sg = g / (1.0f + __expf(-g));
                int row = m0 + wm * 128 + mf * 16 + rQ + r;
                u[(size_t)row * I_ + ch] = f2bf(a * sg);
            }
        }
    }
}

// ---------------- depthwise conv K=31 + bias + PReLU: u bf16 -> v bf16 ----------------
__global__ __launch_bounds__(256) void dwconv_kernel(
    const unsigned short* __restrict__ u, const float* __restrict__ dw,
    const float* __restrict__ dwb, const float* __restrict__ alpha,
    unsigned short* __restrict__ v)
{
    __shared__ __align__(16) unsigned short su[286][64];
    const int tid     = threadIdx.x;
    const int c0      = blockIdx.y * 64;
    const int b       = blockIdx.z;
    const int tile_t0 = blockIdx.x * 256;

    #pragma unroll
    for (int it = 0; it < 9; ++it) {
        int r = it * 32 + (tid >> 3);
        if (r < 286) {
            int tt = tile_t0 - 15 + r;
            int cc = (tid & 7) * 8;
            uint4 val = {0u, 0u, 0u, 0u};
            if (tt >= 0 && tt < T_)
                val = *(const uint4*)(u + ((size_t)b * T_ + tt) * I_ + c0 + cc);
            *(uint4*)(&su[r][cc]) = val;
        }
    }
    __syncthreads();

    const int c  = tid & 63;
    const int tb = (tid >> 6) * 64;

    float dwk[K_];
    #pragma unroll
    for (int k = 0; k < K_; ++k) dwk[k] = dw[(c0 + c) * K_ + k];
    const float bia = dwb[c0 + c], al = alpha[c0 + c];

    unsigned short* vb = v + ((size_t)b * T_ + tile_t0 + tb) * I_ + c0 + c;

    #pragma unroll
    for (int chk = 0; chk < 4; ++chk) {
        float w[46];
        #pragma unroll
        for (int j = 0; j < 46; ++j)
            w[j] = bf2f(su[tb + chk * 16 + j][c]);
        #pragma unroll
        for (int i = 0; i < 16; ++i) {
            float acc = bia;
            #pragma unroll
            for (int k = 0; k < K_; ++k) acc += w[i + k] * dwk[k];
            float o = acc > 0.f ? acc : al * acc;
            vb[(size_t)(chk * 16 + i) * I_] = f2bf(o);
        }
    }
}

// ---------------- GEMM2: v[32768,1024] x w2b^T + b2 -> out fp32 [32768,512] ----------------
__global__ __launch_bounds__(512, 2) void gemm2_kernel(
    const unsigned short* __restrict__ v,
    const unsigned short* __restrict__ w2b,
    const float* __restrict__ b2,
    float* __restrict__ out)
{
    __shared__ __align__(16) unsigned char lds[131072];
    const int tid  = threadIdx.x;
    const int lane = tid & 63;
    const int wv   = tid >> 6;
    const int wm   = wv >> 2;
    const int wn   = wv & 3;

    const int bid = blockIdx.x;                 // nwg = 256
    const int sw  = (bid & 7) * 32 + (bid >> 3);
    const int n0  = (sw & 1) * 256;
    const int m0  = (sw >> 1) * 256;

    const unsigned short* agA[4];
    const unsigned short* agB[4];
    {
        const int srow = tid >> 3;
        const int scb  = tid & 7;
        #pragma unroll
        for (int j = 0; j < 4; ++j) {
            int row = j * 64 + srow;
            int kk  = (scb ^ (row & 7)) * 8;
            agA[j] = v   + (size_t)(m0 + row) * I_ + kk;
            agB[j] = w2b + (size_t)(n0 + row) * I_ + kk;
        }
    }

    const int l15 = lane & 15;
    const unsigned kq  = (unsigned)((lane >> 4) << 4);
    const unsigned swx = (unsigned)((l15 & 7) << 4);
    const unsigned rA  = (unsigned)(wm * 128 + l15) * 128;
    const unsigned rB  = 32768u + (unsigned)(wn * 64 + l15) * 128;
    const unsigned bA0[2] = {rA + (kq ^ swx),          rA + (kq ^ swx) + 65536u};
    const unsigned bA1[2] = {rA + ((64u + kq) ^ swx),  rA + ((64u + kq) ^ swx) + 65536u};
    const unsigned bB0[2] = {rB + (kq ^ swx),          rB + (kq ^ swx) + 65536u};
    const unsigned bB1[2] = {rB + ((64u + kq) ^ swx),  rB + ((64u + kq) ^ swx) + 65536u};

    f32x4 acc[8][4];
    #pragma unroll
    for (int i = 0; i < 8; ++i)
        #pragma unroll
        for (int n = 0; n < 4; ++n) acc[i][n] = (f32x4){0.f, 0.f, 0.f, 0.f};

    ISSUE6(0); ISSUE2(0);
    asm volatile("s_waitcnt vmcnt(2)" ::: "memory");
    __builtin_amdgcn_s_barrier();

    const int NT = I_ / 64;   // 16
    for (int tt = 0; tt < NT; tt += 2) {
        KTILE(0, 1, true, true);
        const bool more = (tt + 2 < NT);
        KTILE(1, 0, more, more);
    }

    const int rQ = (lane >> 4) * 4;
    #pragma unroll
    for (int nf = 0; nf < 4; ++nf) {
        int col = n0 + wn * 64 + nf * 16 + l15;
        float bb = b2[col];
        #pragma unroll
        for (int mf = 0; mf < 8; ++mf) {
            #pragma unroll
            for (int r = 0; r < 4; ++r) {
                int row = m0 + wm * 128 + mf * 16 + rQ + r;
                out[(size_t)row * D_ + col] = acc[mf][nf][r] + bb;
            }
        }
    }
}

extern "C" void kernel_launch(void* const* d_in, const int* in_sizes, int n_in,
                              void* d_out, int out_size, void* d_ws, size_t ws_size,
                              hipStream_t stream) {
    const float* x     = (const float*)d_in[0];
    const float* ln_g  = (const float*)d_in[1];
    const float* ln_b  = (const float*)d_in[2];
    const float* w1    = (const float*)d_in[3];
    const float* b1    = (const float*)d_in[4];
    const float* dw    = (const float*)d_in[5];
    const float* dwb   = (const float*)d_in[6];
    const float* alpha = (const float*)d_in[7];
    const float* w2    = (const float*)d_in[8];
    const float* b2    = (const float*)d_in[9];
    float* out = (float*)d_out;

    char* ws = (char*)d_ws;
    unsigned short* xn  = (unsigned short*)(ws);                 // 32 MB
    unsigned short* u   = (unsigned short*)(ws + 33554432);      // 64 MB
    unsigned short* v   = (unsigned short*)(ws + 100663296);     // 64 MB
    unsigned short* w1b = (unsigned short*)(ws + 167772160);     // 2 MB
    unsigned short* w2b = (unsigned short*)(ws + 169869312);     // 1 MB

    prep_weights<<<4096, 256, 0, stream>>>(w1, w2, w1b, w2b);
    ln_kernel<<<M_ / 4, 256, 0, stream>>>(x, ln_g, ln_b, xn);
    gemm1_kernel<<<(M_ / 256) * (I_ / 128), 512, 0, stream>>>(xn, w1b, b1, u);  // 1024
    dim3 gc(T_ / 256, I_ / 64, B_);
    dwconv_kernel<<<gc, 256, 0, stream>>>(u, dw, dwb, alpha, v);
    gemm2_kernel<<<(M_ / 256) * (D_ / 256), 512, 0, stream>>>(v, w2b, b2, out); // 256
}